// Round 4
// baseline (278.607 us; speedup 1.0000x reference)
//
#include <hip/hip_runtime.h>
#include <hip/hip_bf16.h>

typedef __bf16 bf16;
typedef bf16 bf16x4 __attribute__((ext_vector_type(4)));
typedef bf16 bf16x8 __attribute__((ext_vector_type(8)));
typedef short s16x4 __attribute__((ext_vector_type(4)));
typedef float f32x4 __attribute__((ext_vector_type(4)));

#define MFMA32(A, B, C) __builtin_amdgcn_mfma_f32_16x16x32_bf16(A, B, C, 0, 0, 0)
#define MFMA16(A, B, C) __builtin_amdgcn_mfma_f32_16x16x16bf16_1k(A, B, C, 0, 0, 0)

static constexpr float SCALE = 0.17677669529663687f;  // 1/sqrt(32)
static constexpr float LOG2E = 1.4426950408889634f;

// ---------------- merged prep: convert x, transpose+convert weights, gather bias
// bias layout (S^T C-layout): rbb[h][qt64][kt64][lane64][r4], value =
//   bias[qrow = qt*16 + (lane&15)][key = kt*16 + (lane>>4)*4 + r] * LOG2E
__global__ __launch_bounds__(256) void k_prep(const float* __restrict__ x,
                                              const float* __restrict__ wqkv,
                                              const float* __restrict__ wout,
                                              const float* __restrict__ table,
                                              const int* __restrict__ ridx,
                                              bf16* __restrict__ xb, bf16* __restrict__ wtq,
                                              bf16* __restrict__ wto, bf16* __restrict__ rbb) {
  const int tid = threadIdx.x;
  const int blk = blockIdx.x;
  if (blk < 2048) {
    int t = blk * 256 + tid;
    const float4* s = reinterpret_cast<const float4*>(x) + (size_t)t * 2;
    float4 a = s[0], c = s[1];
    bf16x8 o;
    o[0] = (bf16)a.x; o[1] = (bf16)a.y; o[2] = (bf16)a.z; o[3] = (bf16)a.w;
    o[4] = (bf16)c.x; o[5] = (bf16)c.y; o[6] = (bf16)c.z; o[7] = (bf16)c.w;
    reinterpret_cast<bf16x8*>(xb)[t] = o;
  } else if (blk < 3072) {
    int t = (blk - 2048) * 256 + tid;
    if (t < 196608) {
      int n = t >> 8, k = t & 255;
      wtq[t] = (bf16)wqkv[k * 768 + n];
    } else {
      int t2 = t - 196608;
      int n = t2 >> 8, k = t2 & 255;
      wto[t2] = (bf16)wout[k * 256 + n];
    }
  } else {
    const int bb2 = blk - 3072;  // (qt,kt) tile
    const int qt = bb2 >> 6, kt = bb2 & 63;
    const int r = tid & 3, lane = tid >> 2;
    const int ln = lane & 15, quad = lane >> 4;
    const int qrow = qt * 16 + ln;
    const int key = kt * 16 + quad * 4 + r;
    const int idx = ridx[qrow * 1024 + key];
    const float4* p = reinterpret_cast<const float4*>(table) + idx * 2;
    float4 a = p[0], c = p[1];
    float vals[8] = {a.x, a.y, a.z, a.w, c.x, c.y, c.z, c.w};
    const int base = bb2 * 256 + tid;
#pragma unroll
    for (int h = 0; h < 8; ++h) rbb[h * 1048576 + base] = (bf16)(vals[h] * LOG2E);
  }
}

// -------------------------------------------------- 128x128x(BK=32) bf16 MFMA GEMM
template <int EPI>
__global__ __launch_bounds__(256) void k_gemm(const bf16* __restrict__ A,
                                              const bf16* __restrict__ Bt,
                                              bf16* __restrict__ q, bf16* __restrict__ kk,
                                              bf16* __restrict__ vt, float* __restrict__ out,
                                              const float* __restrict__ bout) {
  __shared__ __align__(16) bf16 As[128 * 40];
  __shared__ __align__(16) bf16 Bs[128 * 40];
  const int tid = threadIdx.x;
  const int ln = tid & 15, quad = (tid >> 4) & 3, wv = tid >> 6;
  const int wm = (wv >> 1) * 64, wn = (wv & 1) * 64;
  const int m0 = blockIdx.x * 128, n0 = blockIdx.y * 128;
  const int srow = tid >> 2, scg = (tid & 3) * 8;
  f32x4 acc[4][4] = {};

  for (int kt = 0; kt < 256; kt += 32) {
    bf16x8 av0 = *reinterpret_cast<const bf16x8*>(&A[(m0 + srow) * 256 + kt + scg]);
    bf16x8 av1 = *reinterpret_cast<const bf16x8*>(&A[(m0 + 64 + srow) * 256 + kt + scg]);
    bf16x8 bv0 = *reinterpret_cast<const bf16x8*>(&Bt[(n0 + srow) * 256 + kt + scg]);
    bf16x8 bv1 = *reinterpret_cast<const bf16x8*>(&Bt[(n0 + 64 + srow) * 256 + kt + scg]);
    *reinterpret_cast<bf16x8*>(&As[srow * 40 + scg]) = av0;
    *reinterpret_cast<bf16x8*>(&As[(64 + srow) * 40 + scg]) = av1;
    *reinterpret_cast<bf16x8*>(&Bs[srow * 40 + scg]) = bv0;
    *reinterpret_cast<bf16x8*>(&Bs[(64 + srow) * 40 + scg]) = bv1;
    __syncthreads();
    bf16x8 af[4], bfr[4];
#pragma unroll
    for (int i = 0; i < 4; ++i)
      af[i] = *reinterpret_cast<const bf16x8*>(&As[(wm + i * 16 + ln) * 40 + quad * 8]);
#pragma unroll
    for (int i = 0; i < 4; ++i)
      bfr[i] = *reinterpret_cast<const bf16x8*>(&Bs[(wn + i * 16 + ln) * 40 + quad * 8]);
#pragma unroll
    for (int i = 0; i < 4; ++i)
#pragma unroll
      for (int j = 0; j < 4; ++j) acc[i][j] = MFMA32(af[i], bfr[j], acc[i][j]);
    __syncthreads();
  }

  if (EPI == 0) {
    const int colbase = n0 + wn;
    const int seg = colbase >> 8;
    const int cb = colbase & 255;
    const float mul = (seg == 0) ? SCALE * LOG2E : 1.0f;
#pragma unroll
    for (int i = 0; i < 4; ++i) {
      const int gm = m0 + wm + i * 16 + quad * 4;
      const int b = gm >> 10;
#pragma unroll
      for (int j = 0; j < 4; ++j) {
        const int gc = cb + j * 16 + ln;
        const int h = gc >> 5, d = gc & 31;
#pragma unroll
        for (int r = 0; r < 4; ++r) {
          const int nseq = (gm + r) & 1023;
          if (seg == 2) {
            vt[(b * 8 + h) * 32768 + d * 1024 + nseq] = (bf16)acc[i][j][r];
          } else {
            bf16* dst = (seg == 0) ? q : kk;
            dst[(b * 8 + h) * 32768 + nseq * 32 + d] = (bf16)(acc[i][j][r] * mul);
          }
        }
      }
    }
  } else {
#pragma unroll
    for (int j = 0; j < 4; ++j) {
      const int gc = n0 + wn + j * 16 + ln;
      const float bb = bout[gc];
#pragma unroll
      for (int i = 0; i < 4; ++i) {
        const int gm = m0 + wm + i * 16 + quad * 4;
#pragma unroll
        for (int r = 0; r < 4; ++r) out[(size_t)(gm + r) * 256 + gc] = acc[i][j][r] + bb;
      }
    }
  }
}

// ----------------------------------------------------------------- flash attention
// Zero-LDS register flash (S^T = K*Q^T; C-layout == A-layout of K=16 MFMA).
// XCD swizzle: blockIdx = qgroup*128 + bh, so blockIdx%8 == h -> all blocks of a
// head (all batches, all q-tiles) land on one XCD; its L2 keeps that head's
// bias plane + K/V resident instead of 8x cross-XCD replication.
// All three streams (K, bias, V) prefetched one iteration ahead.
__global__ __launch_bounds__(256) void k_flash(const bf16* __restrict__ qs,
                                               const bf16* __restrict__ ks,
                                               const bf16* __restrict__ vtg,
                                               const bf16* __restrict__ rbb,
                                               bf16* __restrict__ ao) {
  const int tid = threadIdx.x;
  const int lane = tid & 63;
  const int ln = lane & 15, quad = lane >> 4, wv = tid >> 6;
  const int blk = blockIdx.x;
  const int bh = blk & 127;                 // %8 == h -> XCD affinity
  const int b = bh >> 3, h = bh & 7;
  const int qtw = (blk >> 7) * 4 + wv;      // 16-row q-tile index [0,64)
  const int q0 = qtw * 16;
  const bf16* qb = qs + bh * 32768;
  const bf16* kb = ks + bh * 32768;
  const bf16* vb = vtg + bh * 32768;
  const bf16* bbias = rbb + h * 1048576 + qtw * 16384 + lane * 4;  // + kt16*256

  // Q as B-operand: B[k=d=quad*8+j][n=qrow=ln]
  const bf16x8 qfrag = *reinterpret_cast<const bf16x8*>(&qb[(q0 + ln) * 32 + quad * 8]);

  f32x4 acc00 = {0.f, 0.f, 0.f, 0.f}, acc01 = {0.f, 0.f, 0.f, 0.f};
  f32x4 acc10 = {0.f, 0.f, 0.f, 0.f}, acc11 = {0.f, 0.f, 0.f, 0.f};
  float lsum = 0.f;

  bf16x8 kf[2][4];
  bf16x4 cb[2][4];
  s16x4 vf[2][2][4];
#pragma unroll
  for (int nt = 0; nt < 4; ++nt) {
    kf[0][nt] = *reinterpret_cast<const bf16x8*>(&kb[(nt * 16 + ln) * 32 + quad * 8]);
    cb[0][nt] = *reinterpret_cast<const bf16x4*>(&bbias[nt * 256]);
    vf[0][0][nt] = *reinterpret_cast<const s16x4*>(&vb[ln * 1024 + nt * 16 + quad * 4]);
    vf[0][1][nt] = *reinterpret_cast<const s16x4*>(&vb[(16 + ln) * 1024 + nt * 16 + quad * 4]);
  }

#define STEP(CUR, NXT, IT)                                                                  \
  {                                                                                         \
    const int k0 = (IT) * 64;                                                               \
    f32x4 s[4];                                                                             \
    _Pragma("unroll") for (int nt = 0; nt < 4; ++nt) {                                      \
      f32x4 c;                                                                              \
      _Pragma("unroll") for (int e = 0; e < 4; ++e) c[e] = (float)cb[CUR][nt][e];           \
      s[nt] = MFMA32(kf[CUR][nt], qfrag, c);                                                \
    }                                                                                       \
    _Pragma("unroll") for (int nt = 0; nt < 4; ++nt) {                                      \
      kf[NXT][nt] =                                                                         \
          *reinterpret_cast<const bf16x8*>(&kb[(k0 + 64 + nt * 16 + ln) * 32 + quad * 8]);  \
      cb[NXT][nt] = *reinterpret_cast<const bf16x4*>(&bbias[((IT) * 4 + 4 + nt) * 256]);    \
      vf[NXT][0][nt] =                                                                      \
          *reinterpret_cast<const s16x4*>(&vb[ln * 1024 + k0 + 64 + nt * 16 + quad * 4]);   \
      vf[NXT][1][nt] = *reinterpret_cast<const s16x4*>(                                     \
          &vb[(16 + ln) * 1024 + k0 + 64 + nt * 16 + quad * 4]);                            \
    }                                                                                       \
    s16x4 p[4];                                                                             \
    _Pragma("unroll") for (int nt = 0; nt < 4; ++nt) {                                      \
      bf16x4 t;                                                                             \
      _Pragma("unroll") for (int e = 0; e < 4; ++e) {                                       \
        s[nt][e] = __builtin_amdgcn_exp2f(s[nt][e]);                                        \
        t[e] = (bf16)s[nt][e];                                                              \
      }                                                                                     \
      lsum += (s[nt][0] + s[nt][1]) + (s[nt][2] + s[nt][3]);                                \
      p[nt] = __builtin_bit_cast(s16x4, t);                                                 \
    }                                                                                       \
    acc00 = MFMA16(p[0], vf[CUR][0][0], acc00);                                             \
    acc10 = MFMA16(p[0], vf[CUR][1][0], acc10);                                             \
    acc01 = MFMA16(p[1], vf[CUR][0][1], acc01);                                             \
    acc11 = MFMA16(p[1], vf[CUR][1][1], acc11);                                             \
    acc00 = MFMA16(p[2], vf[CUR][0][2], acc00);                                             \
    acc10 = MFMA16(p[2], vf[CUR][1][2], acc10);                                             \
    acc01 = MFMA16(p[3], vf[CUR][0][3], acc01);                                             \
    acc11 = MFMA16(p[3], vf[CUR][1][3], acc11);                                             \
  }

#pragma unroll 1
  for (int it2 = 0; it2 < 8; ++it2) {
    STEP(0, 1, 2 * it2)
    STEP(1, 0, 2 * it2 + 1)
  }
#undef STEP

  // total row sum for qrow=ln: combine the 4 quads' key partials
  lsum += __shfl_xor(lsum, 16, 64);
  lsum += __shfl_xor(lsum, 32, 64);

  f32x4 a0 = acc00 + acc01;  // O[qrow=quad*4+r][d=ln]
  f32x4 a1 = acc10 + acc11;  // O[qrow=quad*4+r][d=16+ln]
#pragma unroll
  for (int r = 0; r < 4; ++r) {
    const float inv = __builtin_amdgcn_rcpf(__shfl(lsum, quad * 4 + r, 64));
    const int row = q0 + quad * 4 + r;
    bf16* po = &ao[(size_t)(b * 1024 + row) * 256 + h * 32 + ln];
    po[0] = (bf16)(a0[r] * inv);
    po[16] = (bf16)(a1[r] * inv);
  }
}

// ---------------------------------------------------------------------- launcher
extern "C" void kernel_launch(void* const* d_in, const int* in_sizes, int n_in,
                              void* d_out, int out_size, void* d_ws, size_t ws_size,
                              hipStream_t stream) {
  const float* x = (const float*)d_in[0];
  const float* wqkv = (const float*)d_in[1];
  const float* wout = (const float*)d_in[2];
  const float* bout = (const float*)d_in[3];
  const float* btab = (const float*)d_in[4];
  const int* ridx = (const int*)d_in[5];
  float* out = (float*)d_out;

  char* ws = (char*)d_ws;
  bf16* xb  = (bf16*)(ws + 0);           // 8 MB   [16384][256]
  bf16* wtq = (bf16*)(ws + 8388608);     // 384 KB
  bf16* wto = (bf16*)(ws + 8781824);     // 128 KB
  bf16* q   = (bf16*)(ws + 8912896);     // 8 MB   [b,h,n,d] (pre-scaled scale*log2e)
  bf16* k   = (bf16*)(ws + 17301504);    // 8 MB   [b,h,n,d]
  bf16* vt  = (bf16*)(ws + 25690112);    // 8 MB   [b,h,d,n]
  bf16* rb  = (bf16*)(ws + 34078720);    // 16 MB  S^T C-layout bias tiles (*log2e)
  bf16* ao  = (bf16*)(ws + 50855936);    // 8 MB   [16384][256]

  k_prep<<<7168, 256, 0, stream>>>(x, wqkv, wout, btab, ridx, xb, wtq, wto, rb);
  k_gemm<0><<<dim3(128, 6), 256, 0, stream>>>(xb, wtq, q, k, vt, nullptr, nullptr);
  k_flash<<<2048, 256, 0, stream>>>(q, k, vt, rb, ao);
  k_gemm<1><<<dim3(128, 2), 256, 0, stream>>>(ao, wto, nullptr, nullptr, nullptr, out, bout);
}

// Round 5
// 273.186 us; speedup vs baseline: 1.0198x; 1.0198x over previous
//
#include <hip/hip_runtime.h>
#include <hip/hip_bf16.h>

typedef __bf16 bf16;
typedef bf16 bf16x4 __attribute__((ext_vector_type(4)));
typedef bf16 bf16x8 __attribute__((ext_vector_type(8)));
typedef short s16x4 __attribute__((ext_vector_type(4)));
typedef float f32x4 __attribute__((ext_vector_type(4)));

#define MFMA32(A, B, C) __builtin_amdgcn_mfma_f32_16x16x32_bf16(A, B, C, 0, 0, 0)
#define MFMA16(A, B, C) __builtin_amdgcn_mfma_f32_16x16x16bf16_1k(A, B, C, 0, 0, 0)

static constexpr float SCALE = 0.17677669529663687f;  // 1/sqrt(32)
static constexpr float LOG2E = 1.4426950408889634f;

// ---------------- merged prep: convert x, transpose+convert weights, gather bias
// bias layout (S^T C-layout): rbb[h][qt64][kt64][lane64][r4], value =
//   bias[qrow = qt*16 + (lane&15)][key = kt*16 + (lane>>4)*4 + r] * LOG2E
__global__ __launch_bounds__(256) void k_prep(const float* __restrict__ x,
                                              const float* __restrict__ wqkv,
                                              const float* __restrict__ wout,
                                              const float* __restrict__ table,
                                              const int* __restrict__ ridx,
                                              bf16* __restrict__ xb, bf16* __restrict__ wtq,
                                              bf16* __restrict__ wto, bf16* __restrict__ rbb) {
  const int tid = threadIdx.x;
  const int blk = blockIdx.x;
  if (blk < 2048) {
    int t = blk * 256 + tid;
    const float4* s = reinterpret_cast<const float4*>(x) + (size_t)t * 2;
    float4 a = s[0], c = s[1];
    bf16x8 o;
    o[0] = (bf16)a.x; o[1] = (bf16)a.y; o[2] = (bf16)a.z; o[3] = (bf16)a.w;
    o[4] = (bf16)c.x; o[5] = (bf16)c.y; o[6] = (bf16)c.z; o[7] = (bf16)c.w;
    reinterpret_cast<bf16x8*>(xb)[t] = o;
  } else if (blk < 3072) {
    int t = (blk - 2048) * 256 + tid;
    if (t < 196608) {
      int n = t >> 8, k = t & 255;
      wtq[t] = (bf16)wqkv[k * 768 + n];
    } else {
      int t2 = t - 196608;
      int n = t2 >> 8, k = t2 & 255;
      wto[t2] = (bf16)wout[k * 256 + n];
    }
  } else {
    const int bb2 = blk - 3072;  // (qt,kt) tile
    const int qt = bb2 >> 6, kt = bb2 & 63;
    const int r = tid & 3, lane = tid >> 2;
    const int ln = lane & 15, quad = lane >> 4;
    const int qrow = qt * 16 + ln;
    const int key = kt * 16 + quad * 4 + r;
    const int idx = ridx[qrow * 1024 + key];
    const float4* p = reinterpret_cast<const float4*>(table) + idx * 2;
    float4 a = p[0], c = p[1];
    float vals[8] = {a.x, a.y, a.z, a.w, c.x, c.y, c.z, c.w};
    const int base = bb2 * 256 + tid;
#pragma unroll
    for (int h = 0; h < 8; ++h) rbb[h * 1048576 + base] = (bf16)(vals[h] * LOG2E);
  }
}

// -------------------------------------------------- 128x128x(BK=32) bf16 MFMA GEMM
template <int EPI>
__global__ __launch_bounds__(256) void k_gemm(const bf16* __restrict__ A,
                                              const bf16* __restrict__ Bt,
                                              bf16* __restrict__ q, bf16* __restrict__ kk,
                                              bf16* __restrict__ vt, float* __restrict__ out,
                                              const float* __restrict__ bout) {
  __shared__ __align__(16) bf16 As[128 * 40];
  __shared__ __align__(16) bf16 Bs[128 * 40];
  const int tid = threadIdx.x;
  const int ln = tid & 15, quad = (tid >> 4) & 3, wv = tid >> 6;
  const int wm = (wv >> 1) * 64, wn = (wv & 1) * 64;
  const int m0 = blockIdx.x * 128, n0 = blockIdx.y * 128;
  const int srow = tid >> 2, scg = (tid & 3) * 8;
  f32x4 acc[4][4] = {};

  for (int kt = 0; kt < 256; kt += 32) {
    bf16x8 av0 = *reinterpret_cast<const bf16x8*>(&A[(m0 + srow) * 256 + kt + scg]);
    bf16x8 av1 = *reinterpret_cast<const bf16x8*>(&A[(m0 + 64 + srow) * 256 + kt + scg]);
    bf16x8 bv0 = *reinterpret_cast<const bf16x8*>(&Bt[(n0 + srow) * 256 + kt + scg]);
    bf16x8 bv1 = *reinterpret_cast<const bf16x8*>(&Bt[(n0 + 64 + srow) * 256 + kt + scg]);
    *reinterpret_cast<bf16x8*>(&As[srow * 40 + scg]) = av0;
    *reinterpret_cast<bf16x8*>(&As[(64 + srow) * 40 + scg]) = av1;
    *reinterpret_cast<bf16x8*>(&Bs[srow * 40 + scg]) = bv0;
    *reinterpret_cast<bf16x8*>(&Bs[(64 + srow) * 40 + scg]) = bv1;
    __syncthreads();
    bf16x8 af[4], bfr[4];
#pragma unroll
    for (int i = 0; i < 4; ++i)
      af[i] = *reinterpret_cast<const bf16x8*>(&As[(wm + i * 16 + ln) * 40 + quad * 8]);
#pragma unroll
    for (int i = 0; i < 4; ++i)
      bfr[i] = *reinterpret_cast<const bf16x8*>(&Bs[(wn + i * 16 + ln) * 40 + quad * 8]);
#pragma unroll
    for (int i = 0; i < 4; ++i)
#pragma unroll
      for (int j = 0; j < 4; ++j) acc[i][j] = MFMA32(af[i], bfr[j], acc[i][j]);
    __syncthreads();
  }

  if (EPI == 0) {
    const int colbase = n0 + wn;
    const int seg = colbase >> 8;
    const int cb = colbase & 255;
    const float mul = (seg == 0) ? SCALE * LOG2E : 1.0f;
#pragma unroll
    for (int i = 0; i < 4; ++i) {
      const int gm = m0 + wm + i * 16 + quad * 4;
      const int b = gm >> 10;
#pragma unroll
      for (int j = 0; j < 4; ++j) {
        const int gc = cb + j * 16 + ln;
        const int h = gc >> 5, d = gc & 31;
#pragma unroll
        for (int r = 0; r < 4; ++r) {
          const int nseq = (gm + r) & 1023;
          if (seg == 2) {
            vt[(b * 8 + h) * 32768 + d * 1024 + nseq] = (bf16)acc[i][j][r];
          } else {
            bf16* dst = (seg == 0) ? q : kk;
            dst[(b * 8 + h) * 32768 + nseq * 32 + d] = (bf16)(acc[i][j][r] * mul);
          }
        }
      }
    }
  } else {
#pragma unroll
    for (int j = 0; j < 4; ++j) {
      const int gc = n0 + wn + j * 16 + ln;
      const float bb = bout[gc];
#pragma unroll
      for (int i = 0; i < 4; ++i) {
        const int gm = m0 + wm + i * 16 + quad * 4;
#pragma unroll
        for (int r = 0; r < 4; ++r) out[(size_t)(gm + r) * 256 + gc] = acc[i][j][r] + bb;
      }
    }
  }
}

// ----------------------------------------------------------------- flash attention
// Zero-LDS register flash (S^T = K*Q^T; QK C-layout == A-layout of K=16 MFMA so
// P feeds PV straight from registers). XCD swizzle: bh = blk&127 puts all blocks
// of head h on XCD h -> that head's bias plane + K/V stay L2-resident.
// K/bias/V all prefetched one iteration ahead. The K-loop is FULLY UNROLLED:
// a rolled loop with register double-buffer arrays forces a vmcnt drain at the
// backedge every iteration (the r3/r4 regression); unrolled, the prefetches
// pipeline freely across iterations.
__global__ __launch_bounds__(256) void k_flash(const bf16* __restrict__ qs,
                                               const bf16* __restrict__ ks,
                                               const bf16* __restrict__ vtg,
                                               const bf16* __restrict__ rbb,
                                               bf16* __restrict__ ao) {
  const int tid = threadIdx.x;
  const int lane = tid & 63;
  const int ln = lane & 15, quad = lane >> 4, wv = tid >> 6;
  const int blk = blockIdx.x;
  const int bh = blk & 127;             // %8 == h -> XCD affinity
  const int b = bh >> 3, h = bh & 7;
  const int qtw = (blk >> 7) * 4 + wv;  // 16-row q-tile index [0,64)
  const int q0 = qtw * 16;
  const bf16* qb = qs + bh * 32768;
  const bf16* kb = ks + bh * 32768;
  const bf16* vb = vtg + bh * 32768;
  const bf16* bbias = rbb + h * 1048576 + qtw * 16384 + lane * 4;  // + kt16*256

  // Q as B-operand: B[k=d=quad*8+j][n=qrow=ln]
  const bf16x8 qfrag = *reinterpret_cast<const bf16x8*>(&qb[(q0 + ln) * 32 + quad * 8]);

  f32x4 acc00 = {0.f, 0.f, 0.f, 0.f}, acc01 = {0.f, 0.f, 0.f, 0.f};
  f32x4 acc10 = {0.f, 0.f, 0.f, 0.f}, acc11 = {0.f, 0.f, 0.f, 0.f};
  float lsum = 0.f;

  bf16x8 kf[2][4];
  bf16x4 cb[2][4];
  s16x4 vf[2][2][4];
#pragma unroll
  for (int nt = 0; nt < 4; ++nt) {
    kf[0][nt] = *reinterpret_cast<const bf16x8*>(&kb[(nt * 16 + ln) * 32 + quad * 8]);
    cb[0][nt] = *reinterpret_cast<const bf16x4*>(&bbias[nt * 256]);
    vf[0][0][nt] = *reinterpret_cast<const s16x4*>(&vb[ln * 1024 + nt * 16 + quad * 4]);
    vf[0][1][nt] = *reinterpret_cast<const s16x4*>(&vb[(16 + ln) * 1024 + nt * 16 + quad * 4]);
  }

#pragma unroll
  for (int it = 0; it < 16; ++it) {
    const int cur = it & 1, nxt = cur ^ 1;
    const int k0 = it * 64;
    // QK^T with bias as C-init (exp2 domain; scale*log2e folded into q)
    f32x4 s[4];
#pragma unroll
    for (int nt = 0; nt < 4; ++nt) {
      f32x4 c;
#pragma unroll
      for (int e = 0; e < 4; ++e) c[e] = (float)cb[cur][nt][e];
      s[nt] = MFMA32(kf[cur][nt], qfrag, c);
    }
    // prefetch next iteration's K, bias, V (compile-time guard: fully unrolled)
    if (it < 15) {
#pragma unroll
      for (int nt = 0; nt < 4; ++nt) {
        kf[nxt][nt] =
            *reinterpret_cast<const bf16x8*>(&kb[(k0 + 64 + nt * 16 + ln) * 32 + quad * 8]);
        cb[nxt][nt] = *reinterpret_cast<const bf16x4*>(&bbias[(it * 4 + 4 + nt) * 256]);
        vf[nxt][0][nt] =
            *reinterpret_cast<const s16x4*>(&vb[ln * 1024 + k0 + 64 + nt * 16 + quad * 4]);
        vf[nxt][1][nt] =
            *reinterpret_cast<const s16x4*>(&vb[(16 + ln) * 1024 + k0 + 64 + nt * 16 + quad * 4]);
      }
    }
    // P = exp2(S); row-sum accumulate; pack to bf16 A-frags (r == j identity)
    s16x4 p[4];
#pragma unroll
    for (int nt = 0; nt < 4; ++nt) {
      bf16x4 t;
#pragma unroll
      for (int e = 0; e < 4; ++e) {
        s[nt][e] = __builtin_amdgcn_exp2f(s[nt][e]);
        t[e] = (bf16)s[nt][e];
      }
      lsum += (s[nt][0] + s[nt][1]) + (s[nt][2] + s[nt][3]);
      p[nt] = __builtin_bit_cast(s16x4, t);
    }
    acc00 = MFMA16(p[0], vf[cur][0][0], acc00);
    acc10 = MFMA16(p[0], vf[cur][1][0], acc10);
    acc01 = MFMA16(p[1], vf[cur][0][1], acc01);
    acc11 = MFMA16(p[1], vf[cur][1][1], acc11);
    acc00 = MFMA16(p[2], vf[cur][0][2], acc00);
    acc10 = MFMA16(p[2], vf[cur][1][2], acc10);
    acc01 = MFMA16(p[3], vf[cur][0][3], acc01);
    acc11 = MFMA16(p[3], vf[cur][1][3], acc11);
  }

  // total row sum for qrow=ln: combine the 4 quads' key partials
  lsum += __shfl_xor(lsum, 16, 64);
  lsum += __shfl_xor(lsum, 32, 64);

  f32x4 a0 = acc00 + acc01;  // O[qrow=quad*4+r][d=ln]
  f32x4 a1 = acc10 + acc11;  // O[qrow=quad*4+r][d=16+ln]
#pragma unroll
  for (int r = 0; r < 4; ++r) {
    const float inv = __builtin_amdgcn_rcpf(__shfl(lsum, quad * 4 + r, 64));
    const int row = q0 + quad * 4 + r;
    bf16* po = &ao[(size_t)(b * 1024 + row) * 256 + h * 32 + ln];
    po[0] = (bf16)(a0[r] * inv);
    po[16] = (bf16)(a1[r] * inv);
  }
}

// ---------------------------------------------------------------------- launcher
extern "C" void kernel_launch(void* const* d_in, const int* in_sizes, int n_in,
                              void* d_out, int out_size, void* d_ws, size_t ws_size,
                              hipStream_t stream) {
  const float* x = (const float*)d_in[0];
  const float* wqkv = (const float*)d_in[1];
  const float* wout = (const float*)d_in[2];
  const float* bout = (const float*)d_in[3];
  const float* btab = (const float*)d_in[4];
  const int* ridx = (const int*)d_in[5];
  float* out = (float*)d_out;

  char* ws = (char*)d_ws;
  bf16* xb  = (bf16*)(ws + 0);           // 8 MB   [16384][256]
  bf16* wtq = (bf16*)(ws + 8388608);     // 384 KB
  bf16* wto = (bf16*)(ws + 8781824);     // 128 KB
  bf16* q   = (bf16*)(ws + 8912896);     // 8 MB   [b,h,n,d] (pre-scaled scale*log2e)
  bf16* k   = (bf16*)(ws + 17301504);    // 8 MB   [b,h,n,d]
  bf16* vt  = (bf16*)(ws + 25690112);    // 8 MB   [b,h,d,n]
  bf16* rb  = (bf16*)(ws + 34078720);    // 16 MB  S^T C-layout bias tiles (*log2e)
  bf16* ao  = (bf16*)(ws + 50855936);    // 8 MB   [16384][256]

  k_prep<<<7168, 256, 0, stream>>>(x, wqkv, wout, btab, ridx, xb, wtq, wto, rb);
  k_gemm<0><<<dim3(128, 6), 256, 0, stream>>>(xb, wtq, q, k, vt, nullptr, nullptr);
  k_flash<<<2048, 256, 0, stream>>>(q, k, vt, rb, ao);
  k_gemm<1><<<dim3(128, 2), 256, 0, stream>>>(ao, wto, nullptr, nullptr, nullptr, out, bout);
}

// Round 6
// 224.504 us; speedup vs baseline: 1.2410x; 1.2168x over previous
//
#include <hip/hip_runtime.h>
#include <hip/hip_bf16.h>

typedef __bf16 bf16;
typedef bf16 bf16x4 __attribute__((ext_vector_type(4)));
typedef bf16 bf16x8 __attribute__((ext_vector_type(8)));
typedef float f32x4 __attribute__((ext_vector_type(4)));

#define MFMA32(A, B, C) __builtin_amdgcn_mfma_f32_16x16x32_bf16(A, B, C, 0, 0, 0)

static constexpr float SCALE = 0.17677669529663687f;  // 1/sqrt(32)
static constexpr float LOG2E = 1.4426950408889634f;

// ---------------- merged prep: convert x, transpose+convert weights, gather bias
// bias layout (S^T C-layout): rbb[h][qt64][kt64][lane64][r4], value =
//   bias[qrow = qt*16 + (lane&15)][key = kt*16 + (lane>>4)*4 + r] * LOG2E
__global__ __launch_bounds__(256) void k_prep(const float* __restrict__ x,
                                              const float* __restrict__ wqkv,
                                              const float* __restrict__ wout,
                                              const float* __restrict__ table,
                                              const int* __restrict__ ridx,
                                              bf16* __restrict__ xb, bf16* __restrict__ wtq,
                                              bf16* __restrict__ wto, bf16* __restrict__ rbb) {
  const int tid = threadIdx.x;
  const int blk = blockIdx.x;
  if (blk < 2048) {
    int t = blk * 256 + tid;
    const float4* s = reinterpret_cast<const float4*>(x) + (size_t)t * 2;
    float4 a = s[0], c = s[1];
    bf16x8 o;
    o[0] = (bf16)a.x; o[1] = (bf16)a.y; o[2] = (bf16)a.z; o[3] = (bf16)a.w;
    o[4] = (bf16)c.x; o[5] = (bf16)c.y; o[6] = (bf16)c.z; o[7] = (bf16)c.w;
    reinterpret_cast<bf16x8*>(xb)[t] = o;
  } else if (blk < 3072) {
    int t = (blk - 2048) * 256 + tid;
    if (t < 196608) {
      int n = t >> 8, k = t & 255;
      wtq[t] = (bf16)wqkv[k * 768 + n];
    } else {
      int t2 = t - 196608;
      int n = t2 >> 8, k = t2 & 255;
      wto[t2] = (bf16)wout[k * 256 + n];
    }
  } else {
    const int bb2 = blk - 3072;  // (qt,kt) tile
    const int qt = bb2 >> 6, kt = bb2 & 63;
    const int r = tid & 3, lane = tid >> 2;
    const int ln = lane & 15, quad = lane >> 4;
    const int qrow = qt * 16 + ln;
    const int key = kt * 16 + quad * 4 + r;
    const int idx = ridx[qrow * 1024 + key];
    const float4* p = reinterpret_cast<const float4*>(table) + idx * 2;
    float4 a = p[0], c = p[1];
    float vals[8] = {a.x, a.y, a.z, a.w, c.x, c.y, c.z, c.w};
    const int base = bb2 * 256 + tid;
#pragma unroll
    for (int h = 0; h < 8; ++h) rbb[h * 1048576 + base] = (bf16)(vals[h] * LOG2E);
  }
}

// -------------------------------------------------- 128x128x(BK=32) bf16 MFMA GEMM
// EPI 0 epilogue: q (*scale*log2e) [b,h,n,d]; k [b,h,n,d];
//   v -> vt[b,h,d,kcol] with WITHIN-64-KEY PERMUTATION kcol: p=(nt,quad,r) -> c=(quad,nt,r)
//   matching the flash P-strip column relabeling (softmax is key-permutation invariant).
template <int EPI>
__global__ __launch_bounds__(256) void k_gemm(const bf16* __restrict__ A,
                                              const bf16* __restrict__ Bt,
                                              bf16* __restrict__ q, bf16* __restrict__ kk,
                                              bf16* __restrict__ vt, float* __restrict__ out,
                                              const float* __restrict__ bout) {
  __shared__ __align__(16) bf16 As[128 * 40];
  __shared__ __align__(16) bf16 Bs[128 * 40];
  const int tid = threadIdx.x;
  const int ln = tid & 15, quad = (tid >> 4) & 3, wv = tid >> 6;
  const int wm = (wv >> 1) * 64, wn = (wv & 1) * 64;
  const int m0 = blockIdx.x * 128, n0 = blockIdx.y * 128;
  const int srow = tid >> 2, scg = (tid & 3) * 8;
  f32x4 acc[4][4] = {};

  for (int kt = 0; kt < 256; kt += 32) {
    bf16x8 av0 = *reinterpret_cast<const bf16x8*>(&A[(m0 + srow) * 256 + kt + scg]);
    bf16x8 av1 = *reinterpret_cast<const bf16x8*>(&A[(m0 + 64 + srow) * 256 + kt + scg]);
    bf16x8 bv0 = *reinterpret_cast<const bf16x8*>(&Bt[(n0 + srow) * 256 + kt + scg]);
    bf16x8 bv1 = *reinterpret_cast<const bf16x8*>(&Bt[(n0 + 64 + srow) * 256 + kt + scg]);
    *reinterpret_cast<bf16x8*>(&As[srow * 40 + scg]) = av0;
    *reinterpret_cast<bf16x8*>(&As[(64 + srow) * 40 + scg]) = av1;
    *reinterpret_cast<bf16x8*>(&Bs[srow * 40 + scg]) = bv0;
    *reinterpret_cast<bf16x8*>(&Bs[(64 + srow) * 40 + scg]) = bv1;
    __syncthreads();
    bf16x8 af[4], bfr[4];
#pragma unroll
    for (int i = 0; i < 4; ++i)
      af[i] = *reinterpret_cast<const bf16x8*>(&As[(wm + i * 16 + ln) * 40 + quad * 8]);
#pragma unroll
    for (int i = 0; i < 4; ++i)
      bfr[i] = *reinterpret_cast<const bf16x8*>(&Bs[(wn + i * 16 + ln) * 40 + quad * 8]);
#pragma unroll
    for (int i = 0; i < 4; ++i)
#pragma unroll
      for (int j = 0; j < 4; ++j) acc[i][j] = MFMA32(af[i], bfr[j], acc[i][j]);
    __syncthreads();
  }

  if (EPI == 0) {
    const int colbase = n0 + wn;
    const int seg = colbase >> 8;
    const int cb = colbase & 255;
    const float mul = (seg == 0) ? SCALE * LOG2E : 1.0f;
#pragma unroll
    for (int i = 0; i < 4; ++i) {
      const int gm = m0 + wm + i * 16 + quad * 4;
      const int b = gm >> 10;
#pragma unroll
      for (int j = 0; j < 4; ++j) {
        const int gc = cb + j * 16 + ln;
        const int h = gc >> 5, d = gc & 31;
#pragma unroll
        for (int r = 0; r < 4; ++r) {
          const int nseq = (gm + r) & 1023;
          if (seg == 2) {
            const int p6 = nseq & 63;  // permute within 64-key group: (nt,quad,r)->(quad,nt,r)
            const int c6 = ((p6 >> 2) & 3) * 16 + (p6 >> 4) * 4 + (p6 & 3);
            const int kcol = (nseq & ~63) | c6;
            vt[(b * 8 + h) * 32768 + d * 1024 + kcol] = (bf16)acc[i][j][r];
          } else {
            bf16* dst = (seg == 0) ? q : kk;
            dst[(b * 8 + h) * 32768 + nseq * 32 + d] = (bf16)(acc[i][j][r] * mul);
          }
        }
      }
    }
  } else {
#pragma unroll
    for (int j = 0; j < 4; ++j) {
      const int gc = n0 + wn + j * 16 + ln;
      const float bb = bout[gc];
#pragma unroll
      for (int i = 0; i < 4; ++i) {
        const int gm = m0 + wm + i * 16 + quad * 4;
#pragma unroll
        for (int r = 0; r < 4; ++r) out[(size_t)(gm + r) * 256 + gc] = acc[i][j][r] + bb;
      }
    }
  }
}

// ----------------------------------------------------------------- flash attention
// r2 chassis (best measured: full unroll, K+bias 1-deep register prefetch, V loads
// in-iteration, per-wave double-buffered LDS strip, NO __syncthreads — wave
// lockstep + lgkmcnt(0)) with the key-permutation packing:
// QK swapped (S^T = K*Q^T): lane(quad,ln) holds P[qrow=ln][key p=nt*16+quad*4+r].
// Relabel strip cols c = quad*16+nt*4+r -> one lane's 16 values are CONTIGUOUS:
// per iter just 2x ds_write_b128 + 2x ds_read_b128 (vs r2's 16 scalar writes).
// V^T is pre-permuted identically (gemm epilogue), bias tiles already match S^T.
__global__ __launch_bounds__(256) void k_flash(const bf16* __restrict__ qs,
                                               const bf16* __restrict__ ks,
                                               const bf16* __restrict__ vtg,
                                               const bf16* __restrict__ rbb,
                                               bf16* __restrict__ ao) {
  __shared__ __align__(16) bf16 lds_p[4][2][16][72];  // 144B row stride
  const int tid = threadIdx.x;
  const int lane = tid & 63;
  const int ln = lane & 15, quad = lane >> 4, wv = tid >> 6;
  const int blk = blockIdx.x;
  const int bh = blk >> 4;                 // r2 grid mapping (best measured)
  const int b = bh >> 3, h = bh & 7;
  const int qtw = (blk & 15) * 4 + wv;     // 16-row q-tile index [0,64)
  const int q0 = qtw * 16;
  const bf16* qb = qs + bh * 32768;
  const bf16* kb = ks + bh * 32768;
  const bf16* vb = vtg + bh * 32768;
  const bf16* bbias = rbb + h * 1048576 + qtw * 16384 + lane * 4;  // + kt16*256

  // Q as B-operand: B[k=d=quad*8+j][n=qrow=ln]
  const bf16x8 qfrag = *reinterpret_cast<const bf16x8*>(&qb[(q0 + ln) * 32 + quad * 8]);

  f32x4 acc0 = {0.f, 0.f, 0.f, 0.f}, acc1 = {0.f, 0.f, 0.f, 0.f};
  float lsum = 0.f;

  bf16x8 kf[2][4];
  bf16x4 cbf[2][4];
#pragma unroll
  for (int nt = 0; nt < 4; ++nt) {
    kf[0][nt] = *reinterpret_cast<const bf16x8*>(&kb[(nt * 16 + ln) * 32 + quad * 8]);
    cbf[0][nt] = *reinterpret_cast<const bf16x4*>(&bbias[nt * 256]);
  }

#pragma unroll
  for (int it = 0; it < 16; ++it) {
    const int cur = it & 1, nxt = cur ^ 1;
    const int k0 = it * 64;
    // V^T frags (permuted layout), issued early; consumed after the LDS round trip
    bf16x8 va0 = *reinterpret_cast<const bf16x8*>(&vb[ln * 1024 + k0 + quad * 8]);
    bf16x8 va1 = *reinterpret_cast<const bf16x8*>(&vb[ln * 1024 + k0 + 32 + quad * 8]);
    bf16x8 vc0 = *reinterpret_cast<const bf16x8*>(&vb[(16 + ln) * 1024 + k0 + quad * 8]);
    bf16x8 vc1 = *reinterpret_cast<const bf16x8*>(&vb[(16 + ln) * 1024 + k0 + 32 + quad * 8]);
    // S^T = K*Q^T with bias C-init (exp2 domain; scale*log2e folded into q)
    f32x4 s[4];
#pragma unroll
    for (int nt = 0; nt < 4; ++nt) {
      f32x4 c;
#pragma unroll
      for (int e = 0; e < 4; ++e) c[e] = (float)cbf[cur][nt][e];
      s[nt] = MFMA32(kf[cur][nt], qfrag, c);
    }
    // prefetch next iteration's K + bias
    if (it < 15) {
#pragma unroll
      for (int nt = 0; nt < 4; ++nt) {
        kf[nxt][nt] =
            *reinterpret_cast<const bf16x8*>(&kb[(k0 + 64 + nt * 16 + ln) * 32 + quad * 8]);
        cbf[nxt][nt] = *reinterpret_cast<const bf16x4*>(&bbias[(it * 4 + 4 + nt) * 256]);
      }
    }
    // P = exp2(S); row sums; pack in c-order (cols quad*16 + nt*4 + r)
#pragma unroll
    for (int nt = 0; nt < 4; ++nt)
#pragma unroll
      for (int e = 0; e < 4; ++e) s[nt][e] = __builtin_amdgcn_exp2f(s[nt][e]);
#pragma unroll
    for (int nt = 0; nt < 4; ++nt) lsum += (s[nt][0] + s[nt][1]) + (s[nt][2] + s[nt][3]);
    bf16x8 lo, hi;
#pragma unroll
    for (int e = 0; e < 4; ++e) {
      lo[e] = (bf16)s[0][e];
      lo[4 + e] = (bf16)s[1][e];
      hi[e] = (bf16)s[2][e];
      hi[4 + e] = (bf16)s[3][e];
    }
    *reinterpret_cast<bf16x8*>(&lds_p[wv][cur][ln][quad * 16]) = lo;
    *reinterpret_cast<bf16x8*>(&lds_p[wv][cur][ln][quad * 16 + 8]) = hi;
    asm volatile("s_waitcnt lgkmcnt(0)" ::: "memory");
    // PV: A = P strip rows (contiguous 16B), B = permuted V^T frags
    bf16x8 pa0 = *reinterpret_cast<const bf16x8*>(&lds_p[wv][cur][ln][quad * 8]);
    bf16x8 pa1 = *reinterpret_cast<const bf16x8*>(&lds_p[wv][cur][ln][32 + quad * 8]);
    acc0 = MFMA32(pa0, va0, acc0);
    acc1 = MFMA32(pa0, vc0, acc1);
    acc0 = MFMA32(pa1, va1, acc0);
    acc1 = MFMA32(pa1, vc1, acc1);
  }

  // full row sum for qrow=ln: combine the 4 quads' key partials
  lsum += __shfl_xor(lsum, 16, 64);
  lsum += __shfl_xor(lsum, 32, 64);

  // O C-layout: lane holds O[row=quad*4+r][col d=ln (acc0) / 16+ln (acc1)]
#pragma unroll
  for (int r = 0; r < 4; ++r) {
    const float inv = __builtin_amdgcn_rcpf(__shfl(lsum, quad * 4 + r, 64));
    const int row = q0 + quad * 4 + r;
    bf16* po = &ao[(size_t)(b * 1024 + row) * 256 + h * 32 + ln];
    po[0] = (bf16)(acc0[r] * inv);
    po[16] = (bf16)(acc1[r] * inv);
  }
}

// ---------------------------------------------------------------------- launcher
extern "C" void kernel_launch(void* const* d_in, const int* in_sizes, int n_in,
                              void* d_out, int out_size, void* d_ws, size_t ws_size,
                              hipStream_t stream) {
  const float* x = (const float*)d_in[0];
  const float* wqkv = (const float*)d_in[1];
  const float* wout = (const float*)d_in[2];
  const float* bout = (const float*)d_in[3];
  const float* btab = (const float*)d_in[4];
  const int* ridx = (const int*)d_in[5];
  float* out = (float*)d_out;

  char* ws = (char*)d_ws;
  bf16* xb  = (bf16*)(ws + 0);           // 8 MB   [16384][256]
  bf16* wtq = (bf16*)(ws + 8388608);     // 384 KB
  bf16* wto = (bf16*)(ws + 8781824);     // 128 KB
  bf16* q   = (bf16*)(ws + 8912896);     // 8 MB   [b,h,n,d] (pre-scaled scale*log2e)
  bf16* k   = (bf16*)(ws + 17301504);    // 8 MB   [b,h,n,d]
  bf16* vt  = (bf16*)(ws + 25690112);    // 8 MB   [b,h,d,n] key-permuted within 64
  bf16* rb  = (bf16*)(ws + 34078720);    // 16 MB  S^T C-layout bias tiles (*log2e)
  bf16* ao  = (bf16*)(ws + 50855936);    // 8 MB   [16384][256]

  k_prep<<<7168, 256, 0, stream>>>(x, wqkv, wout, btab, ridx, xb, wtq, wto, rb);
  k_gemm<0><<<dim3(128, 6), 256, 0, stream>>>(xb, wtq, q, k, vt, nullptr, nullptr);
  k_flash<<<2048, 256, 0, stream>>>(q, k, vt, rb, ao);
  k_gemm<1><<<dim3(128, 2), 256, 0, stream>>>(ao, wto, nullptr, nullptr, nullptr, out, bout);
}

// Round 7
// 159.452 us; speedup vs baseline: 1.7473x; 1.4080x over previous
//
#include <hip/hip_runtime.h>
#include <hip/hip_bf16.h>

typedef __bf16 bf16;
typedef bf16 bf16x4 __attribute__((ext_vector_type(4)));
typedef bf16 bf16x8 __attribute__((ext_vector_type(8)));
typedef float f32x4 __attribute__((ext_vector_type(4)));

#define MFMA32(A, B, C) __builtin_amdgcn_mfma_f32_16x16x32_bf16(A, B, C, 0, 0, 0)
#define GL2LDS16(gp, lp)                                                            \
  __builtin_amdgcn_global_load_lds((const __attribute__((address_space(1))) unsigned int*)(gp), \
                                   (__attribute__((address_space(3))) unsigned int*)(lp), 16, 0, 0)

static constexpr float SCALE = 0.17677669529663687f;  // 1/sqrt(32)
static constexpr float LOG2E = 1.4426950408889634f;

// ---------------- merged prep: convert x, transpose+convert weights, gather bias
// bias layout (S^T C-layout): rbb[h][qt64][kt64][lane64][r4], value =
//   bias[qrow = qt*16 + (lane&15)][key = kt*16 + (lane>>4)*4 + r] * LOG2E
__global__ __launch_bounds__(256) void k_prep(const float* __restrict__ x,
                                              const float* __restrict__ wqkv,
                                              const float* __restrict__ wout,
                                              const float* __restrict__ table,
                                              const int* __restrict__ ridx,
                                              bf16* __restrict__ xb, bf16* __restrict__ wtq,
                                              bf16* __restrict__ wto, bf16* __restrict__ rbb) {
  const int tid = threadIdx.x;
  const int blk = blockIdx.x;
  if (blk < 2048) {
    int t = blk * 256 + tid;
    const float4* s = reinterpret_cast<const float4*>(x) + (size_t)t * 2;
    float4 a = s[0], c = s[1];
    bf16x8 o;
    o[0] = (bf16)a.x; o[1] = (bf16)a.y; o[2] = (bf16)a.z; o[3] = (bf16)a.w;
    o[4] = (bf16)c.x; o[5] = (bf16)c.y; o[6] = (bf16)c.z; o[7] = (bf16)c.w;
    reinterpret_cast<bf16x8*>(xb)[t] = o;
  } else if (blk < 3072) {
    int t = (blk - 2048) * 256 + tid;
    if (t < 196608) {
      int n = t >> 8, k = t & 255;
      wtq[t] = (bf16)wqkv[k * 768 + n];
    } else {
      int t2 = t - 196608;
      int n = t2 >> 8, k = t2 & 255;
      wto[t2] = (bf16)wout[k * 256 + n];
    }
  } else {
    const int bb2 = blk - 3072;  // (qt,kt) tile
    const int qt = bb2 >> 6, kt = bb2 & 63;
    const int r = tid & 3, lane = tid >> 2;
    const int ln = lane & 15, quad = lane >> 4;
    const int qrow = qt * 16 + ln;
    const int key = kt * 16 + quad * 4 + r;
    const int idx = ridx[qrow * 1024 + key];
    const float4* p = reinterpret_cast<const float4*>(table) + idx * 2;
    float4 a = p[0], c = p[1];
    float vals[8] = {a.x, a.y, a.z, a.w, c.x, c.y, c.z, c.w};
    const int base = bb2 * 256 + tid;
#pragma unroll
    for (int h = 0; h < 8; ++h) rbb[h * 1048576 + base] = (bf16)(vals[h] * LOG2E);
  }
}

// -------------------------------------------------- 128x128x(BK=32) bf16 MFMA GEMM
// EPI 0 epilogue: q (*scale*log2e) [b,h,n,d]; k [b,h,n,d];
//   v -> vt[b,h,d,kcol] with within-64-key permutation p=(nt,quad,r) -> c=(quad,nt,r)
template <int EPI>
__global__ __launch_bounds__(256) void k_gemm(const bf16* __restrict__ A,
                                              const bf16* __restrict__ Bt,
                                              bf16* __restrict__ q, bf16* __restrict__ kk,
                                              bf16* __restrict__ vt, float* __restrict__ out,
                                              const float* __restrict__ bout) {
  __shared__ __align__(16) bf16 As[128 * 40];
  __shared__ __align__(16) bf16 Bs[128 * 40];
  const int tid = threadIdx.x;
  const int ln = tid & 15, quad = (tid >> 4) & 3, wv = tid >> 6;
  const int wm = (wv >> 1) * 64, wn = (wv & 1) * 64;
  const int m0 = blockIdx.x * 128, n0 = blockIdx.y * 128;
  const int srow = tid >> 2, scg = (tid & 3) * 8;
  f32x4 acc[4][4] = {};

  for (int kt = 0; kt < 256; kt += 32) {
    bf16x8 av0 = *reinterpret_cast<const bf16x8*>(&A[(m0 + srow) * 256 + kt + scg]);
    bf16x8 av1 = *reinterpret_cast<const bf16x8*>(&A[(m0 + 64 + srow) * 256 + kt + scg]);
    bf16x8 bv0 = *reinterpret_cast<const bf16x8*>(&Bt[(n0 + srow) * 256 + kt + scg]);
    bf16x8 bv1 = *reinterpret_cast<const bf16x8*>(&Bt[(n0 + 64 + srow) * 256 + kt + scg]);
    *reinterpret_cast<bf16x8*>(&As[srow * 40 + scg]) = av0;
    *reinterpret_cast<bf16x8*>(&As[(64 + srow) * 40 + scg]) = av1;
    *reinterpret_cast<bf16x8*>(&Bs[srow * 40 + scg]) = bv0;
    *reinterpret_cast<bf16x8*>(&Bs[(64 + srow) * 40 + scg]) = bv1;
    __syncthreads();
    bf16x8 af[4], bfr[4];
#pragma unroll
    for (int i = 0; i < 4; ++i)
      af[i] = *reinterpret_cast<const bf16x8*>(&As[(wm + i * 16 + ln) * 40 + quad * 8]);
#pragma unroll
    for (int i = 0; i < 4; ++i)
      bfr[i] = *reinterpret_cast<const bf16x8*>(&Bs[(wn + i * 16 + ln) * 40 + quad * 8]);
#pragma unroll
    for (int i = 0; i < 4; ++i)
#pragma unroll
      for (int j = 0; j < 4; ++j) acc[i][j] = MFMA32(af[i], bfr[j], acc[i][j]);
    __syncthreads();
  }

  if (EPI == 0) {
    const int colbase = n0 + wn;
    const int seg = colbase >> 8;
    const int cb = colbase & 255;
    const float mul = (seg == 0) ? SCALE * LOG2E : 1.0f;
#pragma unroll
    for (int i = 0; i < 4; ++i) {
      const int gm = m0 + wm + i * 16 + quad * 4;
      const int b = gm >> 10;
#pragma unroll
      for (int j = 0; j < 4; ++j) {
        const int gc = cb + j * 16 + ln;
        const int h = gc >> 5, d = gc & 31;
#pragma unroll
        for (int r = 0; r < 4; ++r) {
          const int nseq = (gm + r) & 1023;
          if (seg == 2) {
            const int p6 = nseq & 63;
            const int c6 = ((p6 >> 2) & 3) * 16 + (p6 >> 4) * 4 + (p6 & 3);
            const int kcol = (nseq & ~63) | c6;
            vt[(b * 8 + h) * 32768 + d * 1024 + kcol] = (bf16)acc[i][j][r];
          } else {
            bf16* dst = (seg == 0) ? q : kk;
            dst[(b * 8 + h) * 32768 + nseq * 32 + d] = (bf16)(acc[i][j][r] * mul);
          }
        }
      }
    }
  } else {
#pragma unroll
    for (int j = 0; j < 4; ++j) {
      const int gc = n0 + wn + j * 16 + ln;
      const float bb = bout[gc];
#pragma unroll
      for (int i = 0; i < 4; ++i) {
        const int gm = m0 + wm + i * 16 + quad * 4;
#pragma unroll
        for (int r = 0; r < 4; ++r) out[(size_t)(gm + r) * 256 + gc] = acc[i][j][r] + bb;
      }
    }
  }
}

// ----------------------------------------------------------------- flash attention
// Canonical-§5 flash: K-tile + V-tile cooperatively staged via global_load_lds
// (width 16), double-buffered; ONE barrier per 64-key iteration. Prefetch for
// tile i+1 issues right after barrier i and drains at barrier i+1 -> one full
// iteration in flight. K/V VMEM issue drops 4x vs per-wave private loads.
// Math identical to r6 (verified): S^T = K*Q^T with bias C-init; permuted P
// strip b128 round trip; PV via MFMA32 on permuted V^T frags.
// LDS layouts (swizzled so frag reads are 2-way-free, no padding — staging
// must stay lane-contiguous):
//   Ks[buf][seg4][row64][8]   (seg = d-octet; staged by wave seg)
//   Vs[buf][cg8][d32][8]      (cg = key-octet)
__global__ __launch_bounds__(256) void k_flash(const bf16* __restrict__ qs,
                                               const bf16* __restrict__ ks,
                                               const bf16* __restrict__ vtg,
                                               const bf16* __restrict__ rbb,
                                               bf16* __restrict__ ao) {
  __shared__ __align__(16) bf16 Ks[2][2048];
  __shared__ __align__(16) bf16 Vs[2][2048];
  __shared__ __align__(16) bf16 Ps[4][16][72];
  const int tid = threadIdx.x;
  const int lane = tid & 63;
  const int ln = lane & 15, quad = lane >> 4, wv = tid >> 6;
  const int blk = blockIdx.x;
  const int bh = blk & 127;             // %8 == h -> XCD affinity (r4: -2.4x FETCH)
  const int b = bh >> 3, h = bh & 7;
  const int qtw = (blk >> 7) * 4 + wv;  // 16-row q-tile index [0,64)
  const int q0 = qtw * 16;
  const bf16* qb = qs + bh * 32768;
  const bf16* kb = ks + bh * 32768;
  const bf16* vb = vtg + bh * 32768;
  const bf16* bbias = rbb + h * 1048576 + qtw * 16384 + lane * 4;  // + kt16*256

  // staging addresses: flat i = wv*64+lane, LDS dest = base(wv) + lane*16B
  const bf16* kg = kb + lane * 32 + wv * 8;                              // + k0*32
  const bf16* vg = vb + (lane & 31) * 1024 + (wv * 2 + (lane >> 5)) * 8; // + k0
  bf16* kls0 = &Ks[0][wv * 512];
  bf16* vls0 = &Vs[0][wv * 512];
  bf16* kls1 = &Ks[1][wv * 512];
  bf16* vls1 = &Vs[1][wv * 512];

  // Q as B-operand: B[k=d=quad*8+j][n=qrow=ln]
  const bf16x8 qfrag = *reinterpret_cast<const bf16x8*>(&qb[(q0 + ln) * 32 + quad * 8]);

  f32x4 acc0 = {0.f, 0.f, 0.f, 0.f}, acc1 = {0.f, 0.f, 0.f, 0.f};
  float lsum = 0.f;

  bf16x4 cbf[2][4];
#pragma unroll
  for (int nt = 0; nt < 4; ++nt) cbf[0][nt] = *reinterpret_cast<const bf16x4*>(&bbias[nt * 256]);
  // stage tile 0 into buf 0
  GL2LDS16(kg, kls0);
  GL2LDS16(vg, vls0);

#pragma unroll 2
  for (int it = 0; it < 16; ++it) {
    const int cur = it & 1, nxt = cur ^ 1;
    const int k0 = it * 64;
    __syncthreads();  // tile `it` staged (vmcnt drained); prior LDS reads done
    // prefetch tile it+1 into the other buffer (clamped re-stage on last iter)
    const int kpf = (it < 15) ? k0 + 64 : k0;
    GL2LDS16(kg + kpf * 32, cur ? kls0 : kls1);
    GL2LDS16(vg + kpf, cur ? vls0 : vls1);
#pragma unroll
    for (int nt = 0; nt < 4; ++nt)
      cbf[nxt][nt] = *reinterpret_cast<const bf16x4*>(&bbias[((it < 15 ? it + 1 : it) * 4 + nt) * 256]);
    // K frags from LDS: kf[nt] = K[k0+nt*16+ln][quad*8..+7]
    bf16x8 kf[4];
#pragma unroll
    for (int nt = 0; nt < 4; ++nt)
      kf[nt] = *reinterpret_cast<const bf16x8*>(&Ks[cur][quad * 512 + (nt * 16 + ln) * 8]);
    // S^T = K*Q^T with bias C-init (exp2 domain; scale*log2e folded into q)
    f32x4 s[4];
#pragma unroll
    for (int nt = 0; nt < 4; ++nt) {
      f32x4 c;
#pragma unroll
      for (int e = 0; e < 4; ++e) c[e] = (float)cbf[cur][nt][e];
      s[nt] = MFMA32(kf[nt], qfrag, c);
    }
    // V frags from LDS (permuted layout): B[k=key][n=d]
    bf16x8 va0 = *reinterpret_cast<const bf16x8*>(&Vs[cur][quad * 256 + ln * 8]);
    bf16x8 vc0 = *reinterpret_cast<const bf16x8*>(&Vs[cur][quad * 256 + (16 + ln) * 8]);
    bf16x8 va1 = *reinterpret_cast<const bf16x8*>(&Vs[cur][(4 + quad) * 256 + ln * 8]);
    bf16x8 vc1 = *reinterpret_cast<const bf16x8*>(&Vs[cur][(4 + quad) * 256 + (16 + ln) * 8]);
    // P = exp2(S); row sums; pack in c-order (cols quad*16 + nt*4 + r)
#pragma unroll
    for (int nt = 0; nt < 4; ++nt)
#pragma unroll
      for (int e = 0; e < 4; ++e) s[nt][e] = __builtin_amdgcn_exp2f(s[nt][e]);
#pragma unroll
    for (int nt = 0; nt < 4; ++nt) lsum += (s[nt][0] + s[nt][1]) + (s[nt][2] + s[nt][3]);
    bf16x8 lo, hi;
#pragma unroll
    for (int e = 0; e < 4; ++e) {
      lo[e] = (bf16)s[0][e];
      lo[4 + e] = (bf16)s[1][e];
      hi[e] = (bf16)s[2][e];
      hi[4 + e] = (bf16)s[3][e];
    }
    *reinterpret_cast<bf16x8*>(&Ps[wv][ln][quad * 16]) = lo;
    *reinterpret_cast<bf16x8*>(&Ps[wv][ln][quad * 16 + 8]) = hi;
    // PV: A = P strip rows (DS in-order within wave; compiler waits lgkmcnt)
    bf16x8 pa0 = *reinterpret_cast<const bf16x8*>(&Ps[wv][ln][quad * 8]);
    bf16x8 pa1 = *reinterpret_cast<const bf16x8*>(&Ps[wv][ln][32 + quad * 8]);
    acc0 = MFMA32(pa0, va0, acc0);
    acc1 = MFMA32(pa0, vc0, acc1);
    acc0 = MFMA32(pa1, va1, acc0);
    acc1 = MFMA32(pa1, vc1, acc1);
  }

  // full row sum for qrow=ln: combine the 4 quads' key partials
  lsum += __shfl_xor(lsum, 16, 64);
  lsum += __shfl_xor(lsum, 32, 64);

  // O C-layout: lane holds O[row=quad*4+r][col d=ln (acc0) / 16+ln (acc1)]
#pragma unroll
  for (int r = 0; r < 4; ++r) {
    const float inv = __builtin_amdgcn_rcpf(__shfl(lsum, quad * 4 + r, 64));
    const int row = q0 + quad * 4 + r;
    bf16* po = &ao[(size_t)(b * 1024 + row) * 256 + h * 32 + ln];
    po[0] = (bf16)(acc0[r] * inv);
    po[16] = (bf16)(acc1[r] * inv);
  }
}

// ---------------------------------------------------------------------- launcher
extern "C" void kernel_launch(void* const* d_in, const int* in_sizes, int n_in,
                              void* d_out, int out_size, void* d_ws, size_t ws_size,
                              hipStream_t stream) {
  const float* x = (const float*)d_in[0];
  const float* wqkv = (const float*)d_in[1];
  const float* wout = (const float*)d_in[2];
  const float* bout = (const float*)d_in[3];
  const float* btab = (const float*)d_in[4];
  const int* ridx = (const int*)d_in[5];
  float* out = (float*)d_out;

  char* ws = (char*)d_ws;
  bf16* xb  = (bf16*)(ws + 0);           // 8 MB   [16384][256]
  bf16* wtq = (bf16*)(ws + 8388608);     // 384 KB
  bf16* wto = (bf16*)(ws + 8781824);     // 128 KB
  bf16* q   = (bf16*)(ws + 8912896);     // 8 MB   [b,h,n,d] (pre-scaled scale*log2e)
  bf16* k   = (bf16*)(ws + 17301504);    // 8 MB   [b,h,n,d]
  bf16* vt  = (bf16*)(ws + 25690112);    // 8 MB   [b,h,d,n] key-permuted within 64
  bf16* rb  = (bf16*)(ws + 34078720);    // 16 MB  S^T C-layout bias tiles (*log2e)
  bf16* ao  = (bf16*)(ws + 50855936);    // 8 MB   [16384][256]

  k_prep<<<7168, 256, 0, stream>>>(x, wqkv, wout, btab, ridx, xb, wtq, wto, rb);
  k_gemm<0><<<dim3(128, 6), 256, 0, stream>>>(xb, wtq, q, k, vt, nullptr, nullptr);
  k_flash<<<2048, 256, 0, stream>>>(q, k, vt, rb, ao);
  k_gemm<1><<<dim3(128, 2), 256, 0, stream>>>(ao, wto, nullptr, nullptr, nullptr, out, bout);
}